// Round 7
// baseline (220.154 us; speedup 1.0000x reference)
//
#include <hip/hip_runtime.h>

#define N_NODES 50000
#define N_EDGES 300000
#define M_PAD 50048    // 391 * 128 (QKV GEMM row padding)
#define M_PAD2 50176   // 196 * 256 (out GEMM row padding)
#define NBLK 196       // ceil(N_NODES/256)

typedef __attribute__((ext_vector_type(8))) short bf16x8;
typedef __attribute__((ext_vector_type(4))) short bf16x4;
typedef __attribute__((ext_vector_type(4))) float f32x4;

__device__ __forceinline__ float bf2f(unsigned short h) { return __uint_as_float(((unsigned int)h) << 16); }
__device__ __forceinline__ unsigned short f2bf(float x) {
    unsigned int u = __float_as_uint(x);
    unsigned int r = (u + 0x7FFFu + ((u >> 16) & 1u)) >> 16;
    return (unsigned short)r;
}

// ---------------------------------------------------------------------------
// Fragment-direct MFMA GEMM (no operand LDS, no K-loop barriers).
//   C[BM x BN] = A2[.. x 256](bf16) @ B2[.. x 256](bf16)^T
//   512 threads = 8 waves; wave tile 64x64; K-loop 8 x (16x16x32 MFMA).
// MODE 0: BM=128, BN=256, grid(3, 391): bx selects Q/K/V. Epilogue stages C
//         in swizzled LDS -> coalesced 16B stores (V stored transposed [d][g]).
// MODE 1: BM=256, BN=128, grid(1, 196): fp32 out + cnt4-weighted eew/bo bias.
// ---------------------------------------------------------------------------
template <int MODE>
__global__ __launch_bounds__(512)
void mfma_gemm(const unsigned short* __restrict__ A2, const unsigned short* __restrict__ B2,
               const float* __restrict__ biasCat,
               unsigned short* __restrict__ Qb, unsigned short* __restrict__ Kb,
               unsigned short* __restrict__ Vb,
               const float* __restrict__ eew, const float* __restrict__ bo,
               const float4* __restrict__ cnt4, float* __restrict__ Cout)
{
    constexpr int K2  = 256;
    constexpr int NWN = (MODE == 0) ? 4 : 2;            // waves along N
    const int t    = threadIdx.x;
    const int w    = t >> 6;
    const int lane = t & 63;
    const int l15  = lane & 15;
    const int lg   = lane >> 4;
    const int bx   = blockIdx.x;
    const int m0   = blockIdx.y * ((MODE == 0) ? 128 : 256);
    const int n0   = bx * (NWN * 64);
    const int wm   = (w / NWN) * 64;
    const int wn   = (w % NWN) * 64;

    f32x4 acc[4][4] = {};

    const unsigned short* Abase = A2 + (size_t)(m0 + wm + l15) * K2 + lg * 8;
    const unsigned short* Bbase = B2 + (size_t)(n0 + wn + l15) * K2 + lg * 8;

    #pragma unroll 2
    for (int ks = 0; ks < 8; ++ks) {
        bf16x8 af[4], bfv[4];
        #pragma unroll
        for (int mi = 0; mi < 4; ++mi)
            af[mi] = *(const bf16x8*)(Abase + (size_t)mi * 16 * K2 + ks * 32);
        #pragma unroll
        for (int ni = 0; ni < 4; ++ni)
            bfv[ni] = *(const bf16x8*)(Bbase + (size_t)ni * 16 * K2 + ks * 32);
        #pragma unroll
        for (int mi = 0; mi < 4; ++mi)
            #pragma unroll
            for (int ni = 0; ni < 4; ++ni)
                acc[mi][ni] = __builtin_amdgcn_mfma_f32_16x16x32_bf16(
                    af[mi], bfv[ni], acc[mi][ni], 0, 0, 0);
    }

    if constexpr (MODE == 0) {
        // ---- stage C in swizzled LDS, then coalesced stores ----
        __shared__ unsigned short Cs[128 * 256];        // 64 KB
        float bvn[4];
        #pragma unroll
        for (int ni = 0; ni < 4; ++ni)
            bvn[ni] = biasCat[n0 + wn + ni * 16 + l15];
        #pragma unroll
        for (int mi = 0; mi < 4; ++mi)
            #pragma unroll
            for (int j = 0; j < 4; ++j) {
                const int row = wm + mi * 16 + lg * 4 + j;
                const int xr  = (row & 7) << 3;
                #pragma unroll
                for (int ni = 0; ni < 4; ++ni) {
                    const int col = wn + ni * 16 + l15;
                    Cs[row * 256 + (col ^ xr)] = f2bf(acc[mi][ni][j] + bvn[ni]);
                }
            }
        __syncthreads();

        if (bx < 2) {
            unsigned short* dst = bx ? Kb : Qb;
            #pragma unroll
            for (int c8 = 0; c8 < 8; ++c8) {
                const int chunk = c8 * 512 + t;
                const int row = chunk >> 5;
                const int ec  = (chunk & 31) * 8;
                const bf16x8 v = *(const bf16x8*)&Cs[row * 256 + (ec ^ ((row & 7) << 3))];
                *(bf16x8*)&dst[(size_t)(m0 + row) * 256 + ec] = v;
            }
        } else {
            // V transposed: element idx = d*8+g  <-  source col c = g*32+d
            #pragma unroll
            for (int c8 = 0; c8 < 8; ++c8) {
                const int chunk = c8 * 512 + t;
                const int row = chunk >> 5;
                const int ec  = (chunk & 31) * 8;
                const int d   = ec >> 3;
                const int xr  = (row & 7) << 3;
                bf16x8 v;
                #pragma unroll
                for (int g = 0; g < 8; ++g)
                    v[g] = (short)Cs[row * 256 + ((g * 32 + d) ^ xr)];
                *(bf16x8*)&Vb[(size_t)(m0 + row) * 256 + ec] = v;
            }
        }
    } else {
        // ---- fp32 out + cnt-weighted bias, direct stores ----
        #pragma unroll
        for (int mi = 0; mi < 4; ++mi)
            #pragma unroll
            for (int j = 0; j < 4; ++j) {
                const int row = m0 + wm + mi * 16 + lg * 4 + j;
                if (row < N_NODES) {
                    const float4 cv = cnt4[row];
                    #pragma unroll
                    for (int ni = 0; ni < 4; ++ni) {
                        const int col = wn + ni * 16 + l15;
                        Cout[(size_t)row * 128 + col] = acc[mi][ni][j]
                            + cv.x * eew[col] + cv.y * eew[128 + col]
                            + cv.z * eew[256 + col] + cv.w * bo[col];
                    }
                }
            }
    }
}

// ---------------------------------------------------------------------------
// Conversions / weight prep
// ---------------------------------------------------------------------------
__global__ __launch_bounds__(256)
void conv_nf_kernel(const float4* __restrict__ nf4, unsigned short* __restrict__ A2)
{
    const int tid = blockIdx.x * 256 + threadIdx.x;
    if (tid >= N_NODES * 32) return;
    const int m = tid >> 5, k4 = (tid & 31) * 4;
    const float4 v = nf4[tid];
    ushort4 hi, lo;
    hi.x = f2bf(v.x); lo.x = f2bf(v.x - bf2f(hi.x));
    hi.y = f2bf(v.y); lo.y = f2bf(v.y - bf2f(hi.y));
    hi.z = f2bf(v.z); lo.z = f2bf(v.z - bf2f(hi.z));
    hi.w = f2bf(v.w); lo.w = f2bf(v.w - bf2f(hi.w));
    *reinterpret_cast<ushort4*>(&A2[(size_t)m * 256 + k4]) = hi;
    *reinterpret_cast<ushort4*>(&A2[(size_t)m * 256 + 128 + k4]) = lo;
}

__global__ __launch_bounds__(256)
void prep_kernel(const float* __restrict__ Wq, const float* __restrict__ Wk,
                 const float* __restrict__ Wv, const float* __restrict__ bq,
                 const float* __restrict__ bk, const float* __restrict__ bv,
                 const float* __restrict__ Wo, const float* __restrict__ ee,
                 unsigned short* __restrict__ B2qkv, unsigned short* __restrict__ B2o,
                 float* __restrict__ biasCat, float* __restrict__ eew)
{
    const int bid = blockIdx.x, t = threadIdx.x;
    if (bid < 384) {
        const int tid = bid * 256 + t;          // 768*128
        const int r = tid >> 7, k = tid & 127;
        const float* W = (r < 256) ? Wq : (r < 512) ? Wk : Wv;
        const unsigned short h = f2bf(W[(size_t)(r & 255) * 128 + k]);
        B2qkv[(size_t)r * 256 + k] = h;
        B2qkv[(size_t)r * 256 + 128 + k] = h;
        if (k == 0) {
            const float* b = (r < 256) ? bq : (r < 512) ? bk : bv;
            biasCat[r] = b[r & 255];
        }
    } else if (bid < 512) {
        const int tid = (bid - 384) * 256 + t;  // 128*256
        const int r = tid >> 8, k = tid & 255;
        B2o[(size_t)r * 256 + k] = f2bf(Wo[(size_t)r * 256 + k]);
    } else if (t < 128) {
        float a0 = 0.f, a1 = 0.f, a2 = 0.f;
        for (int k = 0; k < 256; ++k) {
            const float w = Wo[(size_t)t * 256 + k];
            a0 += ee[k] * w; a1 += ee[256 + k] * w; a2 += ee[512 + k] * w;
        }
        eew[t] = a0; eew[128 + t] = a1; eew[256 + t] = a2;
    }
}

// ---------------------------------------------------------------------------
// CSR build: hist -> hierarchical scan -> scatter
// ---------------------------------------------------------------------------
__global__ __launch_bounds__(256)
void hist_kernel(const int* __restrict__ edges, int* __restrict__ deg)
{
    const int e = blockIdx.x * 256 + threadIdx.x;
    if (e < N_EDGES) atomicAdd(&deg[edges[2 * e]], 1);
}

__global__ __launch_bounds__(256)
void scan_part1(const int* __restrict__ deg, int* __restrict__ blockSum)
{
    const int t = threadIdx.x;
    const int i = blockIdx.x * 256 + t;
    int v = (i < N_NODES) ? deg[i] : 0;
    #pragma unroll
    for (int o = 1; o < 64; o <<= 1) v += __shfl_xor(v, o);
    __shared__ int ws[4];
    if ((t & 63) == 0) ws[t >> 6] = v;
    __syncthreads();
    if (t == 0) blockSum[blockIdx.x] = ws[0] + ws[1] + ws[2] + ws[3];
}

__global__ __launch_bounds__(256)
void scan_part2(const int* __restrict__ blockSum, int* __restrict__ blockBase,
                int* __restrict__ rowStart)
{
    __shared__ int lds[256];
    const int t = threadIdx.x;
    lds[t] = (t < NBLK) ? blockSum[t] : 0;
    __syncthreads();
    #pragma unroll
    for (int o = 1; o < 256; o <<= 1) {
        const int u = (t >= o) ? lds[t - o] : 0;
        __syncthreads();
        lds[t] += u;
        __syncthreads();
    }
    if (t < NBLK) blockBase[t] = (t == 0) ? 0 : lds[t - 1];
    if (t == 0) rowStart[N_NODES] = N_EDGES;
}

__global__ __launch_bounds__(256)
void scan_part3(const int* __restrict__ deg, const int* __restrict__ blockBase,
                int* __restrict__ rowStart, int* __restrict__ cursor)
{
    const int t = threadIdx.x;
    const int lane = t & 63, wid = t >> 6;
    const int i = blockIdx.x * 256 + t;
    const int d = (i < N_NODES) ? deg[i] : 0;
    int x = d;
    #pragma unroll
    for (int o = 1; o < 64; o <<= 1) {
        const int u = __shfl_up(x, o);
        if (lane >= o) x += u;
    }
    __shared__ int wtot[4];
    if (lane == 63) wtot[wid] = x;
    __syncthreads();
    int wo = 0;
    #pragma unroll
    for (int wi = 0; wi < 3; ++wi) wo += (wi < wid) ? wtot[wi] : 0;
    const int excl = blockBase[blockIdx.x] + wo + x - d;
    if (i < N_NODES) { rowStart[i] = excl; cursor[i] = excl; }
}

__global__ __launch_bounds__(256)
void scatter_kernel(const int* __restrict__ edges, const int* __restrict__ etypes,
                    int* __restrict__ cursor, int* __restrict__ packed)
{
    const int e = blockIdx.x * 256 + threadIdx.x;
    if (e < N_EDGES) {
        const int pos = atomicAdd(&cursor[edges[2 * e]], 1);
        packed[pos] = edges[2 * e + 1] | (etypes[e] << 20);
    }
}

// ---------------------------------------------------------------------------
// MFMA gather attention (unchanged from R5): one wave per src node,
// 2 edges per iteration as a block-diagonal 16x16 problem.
// ---------------------------------------------------------------------------
__global__ __launch_bounds__(256)
void node_gather_kernel(const int* __restrict__ packed, const int* __restrict__ rowStart,
                        const unsigned short* __restrict__ Qb,
                        const unsigned short* __restrict__ Kb,
                        const unsigned short* __restrict__ Vb,
                        unsigned short* __restrict__ accQ, float4* __restrict__ cnt4)
{
    const int lane = threadIdx.x & 63;
    const int n = blockIdx.x * 4 + (threadIdx.x >> 6);
    if (n >= N_NODES) return;
    const int l15 = lane & 15;
    const int lg  = lane >> 4;

    const bf16x8 qf = *(const bf16x8*)&Qb[(size_t)n * 256 + (l15 & 7) * 32 + lg * 8];

    f32x4 cpv0 = {0.f, 0.f, 0.f, 0.f};
    f32x4 cpv1 = {0.f, 0.f, 0.f, 0.f};
    int c0 = 0, c1 = 0, c2 = 0;

    const int lo = rowStart[n], hi = rowStart[n + 1];
    const bool validBase = ((l15 < 8) == (lg < 2));

    for (int idx = lo; idx < hi; idx += 2) {
        const int  p0  = packed[idx];
        const bool dup = (idx + 1 >= hi);
        const int  p1  = dup ? p0 : packed[idx + 1];
        const int  t0  = p0 & 0xFFFFF;
        const int  t1  = p1 & 0xFFFFF;
        const int  e0  = p0 >> 20;
        const int  e1  = p1 >> 20;
        c0 += (e0 == 0); c1 += (e0 == 1); c2 += (e0 == 2);
        if (!dup) { c0 += (e1 == 0); c1 += (e1 == 1); c2 += (e1 == 2); }

        const int tk = (l15 < 8) ? t0 : t1;
        const bf16x8 kf = *(const bf16x8*)&Kb[(size_t)tk * 256 + (l15 & 7) * 32 + lg * 8];

        const int tv = (lg < 2) ? t0 : t1;
        const unsigned short* vrow = &Vb[(size_t)tv * 256 + (lg & 1) * 4];
        const bf16x4 vf0 = *(const bf16x4*)&vrow[l15 * 8];
        const bf16x4 vf1 = *(const bf16x4*)&vrow[(l15 + 16) * 8];

        f32x4 s = __builtin_amdgcn_mfma_f32_16x16x32_bf16(kf, qf, (f32x4){0.f, 0.f, 0.f, 0.f}, 0, 0, 0);
        const float SC = 0.17677669529663687f;
        const float s0 = s[0] * SC, s1 = s[1] * SC, s2 = s[2] * SC, s3 = s[3] * SC;

        float mx = fmaxf(fmaxf(s0, s1), fmaxf(s2, s3));
        mx = fmaxf(mx, __shfl_xor(mx, 16));
        const float ex0 = __expf(s0 - mx), ex1 = __expf(s1 - mx);
        const float ex2 = __expf(s2 - mx), ex3 = __expf(s3 - mx);
        float sum = ex0 + ex1 + ex2 + ex3;
        sum += __shfl_xor(sum, 16);
        const float inv = 1.0f / sum;

        const bool valid = validBase && !(dup && (l15 >= 8));
        bf16x4 pa;
        pa[0] = valid ? (short)f2bf(ex0 * inv) : (short)0;
        pa[1] = valid ? (short)f2bf(ex1 * inv) : (short)0;
        pa[2] = valid ? (short)f2bf(ex2 * inv) : (short)0;
        pa[3] = valid ? (short)f2bf(ex3 * inv) : (short)0;

        cpv0 = __builtin_amdgcn_mfma_f32_16x16x16bf16_1k(pa, vf0, cpv0, 0, 0, 0);
        cpv1 = __builtin_amdgcn_mfma_f32_16x16x16bf16_1k(pa, vf1, cpv1, 0, 0, 0);
    }

    #pragma unroll
    for (int j = 0; j < 4; ++j) {
        cpv0[j] += __shfl_xor(cpv0[j], 32);
        cpv1[j] += __shfl_xor(cpv1[j], 32);
    }

    if (lane < 32) {
        unsigned short* row = &accQ[(size_t)n * 256];
        #pragma unroll
        for (int j = 0; j < 4; ++j) {
            const int h = lg * 4 + j;
            row[h * 32 + l15]      = f2bf(cpv0[j]);
            row[h * 32 + 16 + l15] = f2bf(cpv1[j]);
        }
    }
    if (lane == 0)
        cnt4[n] = make_float4((float)c0, (float)c1, (float)c2, (float)(hi - lo));
}

// ---------------------------------------------------------------------------
extern "C" void kernel_launch(void* const* d_in, const int* in_sizes, int n_in,
                              void* d_out, int out_size, void* d_ws, size_t ws_size,
                              hipStream_t stream)
{
    const float* nf      = (const float*)d_in[0];
    const int*   edges   = (const int*)d_in[1];
    const int*   etypes  = (const int*)d_in[2];
    const float* Wq      = (const float*)d_in[3];
    const float* bq      = (const float*)d_in[4];
    const float* Wk      = (const float*)d_in[5];
    const float* bk      = (const float*)d_in[6];
    const float* Wv      = (const float*)d_in[7];
    const float* bv      = (const float*)d_in[8];
    const float* ee      = (const float*)d_in[9];
    const float* Wo      = (const float*)d_in[10];
    const float* bo      = (const float*)d_in[11];
    float* out = (float*)d_out;

    char* ws = (char*)d_ws;
    size_t off = 0;
    auto alloc = [&](size_t bytes) -> void* {
        void* p = ws + off;
        off = (off + bytes + 255) & ~(size_t)255;
        return p;
    };
    unsigned short* A2    = (unsigned short*)alloc((size_t)M_PAD * 256 * 2);
    unsigned short* B2qkv = (unsigned short*)alloc((size_t)768 * 256 * 2);
    unsigned short* B2o   = (unsigned short*)alloc((size_t)128 * 256 * 2);
    float*          biasC = (float*)alloc(768 * sizeof(float));
    float*          eew   = (float*)alloc(384 * sizeof(float));
    unsigned short* Qb    = (unsigned short*)alloc((size_t)M_PAD * 256 * 2);
    unsigned short* Kb    = (unsigned short*)alloc((size_t)M_PAD * 256 * 2);
    unsigned short* Vb    = (unsigned short*)alloc((size_t)M_PAD * 256 * 2);
    unsigned short* accQ  = (unsigned short*)alloc((size_t)M_PAD2 * 256 * 2);
    float4* cnt4 = (float4*)alloc((size_t)N_NODES * sizeof(float4));
    int*    deg  = (int*)alloc((size_t)N_NODES * sizeof(int));
    int*    rowS = (int*)alloc((size_t)(N_NODES + 1) * sizeof(int));
    int*    curs = (int*)alloc((size_t)N_NODES * sizeof(int));
    int*    pck  = (int*)alloc((size_t)N_EDGES * sizeof(int));
    int*    bSum = (int*)alloc((size_t)NBLK * sizeof(int));
    int*    bBase= (int*)alloc((size_t)NBLK * sizeof(int));

    const dim3 blk(256);

    // conversions + weight prep
    conv_nf_kernel<<<dim3((N_NODES * 32 + 255) / 256), blk, 0, stream>>>((const float4*)nf, A2);
    prep_kernel<<<dim3(513), blk, 0, stream>>>(Wq, Wk, Wv, bq, bk, bv, Wo, ee, B2qkv, B2o, biasC, eew);

    // CSR build (hierarchical scan)
    hipMemsetAsync(deg, 0, (size_t)N_NODES * sizeof(int), stream);
    hist_kernel<<<dim3((N_EDGES + 255) / 256), blk, 0, stream>>>(edges, deg);
    scan_part1<<<dim3(NBLK), blk, 0, stream>>>(deg, bSum);
    scan_part2<<<dim3(1), blk, 0, stream>>>(bSum, bBase, rowS);
    scan_part3<<<dim3(NBLK), blk, 0, stream>>>(deg, bBase, rowS, curs);
    scatter_kernel<<<dim3((N_EDGES + 255) / 256), blk, 0, stream>>>(edges, etypes, curs, pck);

    // fused QKV projection (fragment-direct MFMA): [50048 x 256] @ [768 x 256]^T
    mfma_gemm<0><<<dim3(3, M_PAD / 128), dim3(512), 0, stream>>>(
        A2, B2qkv, biasC, Qb, Kb, Vb, nullptr, nullptr, nullptr, nullptr);

    // MFMA gather attention
    node_gather_kernel<<<dim3((N_NODES + 3) / 4), blk, 0, stream>>>(
        pck, rowS, Qb, Kb, Vb, accQ, cnt4);

    // output projection (fragment-direct MFMA): [50176 x 256] @ [128 x 256]^T
    mfma_gemm<1><<<dim3(1, M_PAD2 / 256), dim3(512), 0, stream>>>(
        accQ, B2o, nullptr, nullptr, nullptr, nullptr, eew, bo, cnt4, out);
}

// Round 8
// 188.406 us; speedup vs baseline: 1.1685x; 1.1685x over previous
//
#include <hip/hip_runtime.h>

#define N_NODES 50000
#define N_EDGES 300000
#define M_PAD 50048    // 391 * 128 (QKV GEMM row padding)
#define M_PAD2 50176   // 784 * 64  (out GEMM row padding)
#define NBLK 196       // ceil(N_NODES/256)

typedef __attribute__((ext_vector_type(8))) short bf16x8;
typedef __attribute__((ext_vector_type(4))) short bf16x4;
typedef __attribute__((ext_vector_type(4))) float f32x4;

__device__ __forceinline__ float bf2f(unsigned short h) { return __uint_as_float(((unsigned int)h) << 16); }
__device__ __forceinline__ unsigned short f2bf(float x) {
    unsigned int u = __float_as_uint(x);
    unsigned int r = (u + 0x7FFFu + ((u >> 16) & 1u)) >> 16;
    return (unsigned short)r;
}

// ---------------------------------------------------------------------------
// Fragment-direct MFMA GEMM (no operand LDS, no K-loop barriers).
// MODE 0: QKV. A2[M_PAD x 128] bf16, B2[768 x 128] bf16. BM=128, BN=256,
//         512 thr (8 waves 2m x 4n), grid(3, 391); bx 0/1/2 -> Q/K/V.
//         Epilogue: 32 KB swizzled LDS, two passes -> coalesced 16B stores
//         (V stored transposed [d][g]).
// MODE 1: out. A2[M_PAD2 x 256] bf16 (accQ), B2[128 x 256] bf16 (Wo).
//         BM=64, BN=128, 128 thr (2 waves 1m x 2n), grid(1, 784).
//         fp32 out + cnt4-weighted eew/bo bias.
// ---------------------------------------------------------------------------
template <int MODE>
__global__ __launch_bounds__(MODE == 0 ? 512 : 128)
void mfma_gemm(const unsigned short* __restrict__ A2, const unsigned short* __restrict__ B2,
               const float* __restrict__ biasCat,
               unsigned short* __restrict__ Qb, unsigned short* __restrict__ Kb,
               unsigned short* __restrict__ Vb,
               const float* __restrict__ eew, const float* __restrict__ bo,
               const float4* __restrict__ cnt4, float* __restrict__ Cout)
{
    constexpr int K2  = (MODE == 0) ? 128 : 256;
    constexpr int NWN = (MODE == 0) ? 4 : 2;            // waves along N
    constexpr int BM  = (MODE == 0) ? 128 : 64;
    const int t    = threadIdx.x;
    const int w    = t >> 6;
    const int lane = t & 63;
    const int l15  = lane & 15;
    const int lg   = lane >> 4;
    const int bx   = blockIdx.x;
    const int m0   = blockIdx.y * BM;
    const int n0   = bx * (NWN * 64);
    const int wm   = (w / NWN) * 64;
    const int wn   = (w % NWN) * 64;

    f32x4 acc[4][4] = {};

    const unsigned short* Abase = A2 + (size_t)(m0 + wm + l15) * K2 + lg * 8;
    const unsigned short* Bbase = B2 + (size_t)(n0 + wn + l15) * K2 + lg * 8;

    #pragma unroll 2
    for (int ks = 0; ks < K2 / 32; ++ks) {
        bf16x8 af[4], bfv[4];
        #pragma unroll
        for (int mi = 0; mi < 4; ++mi)
            af[mi] = *(const bf16x8*)(Abase + (size_t)mi * 16 * K2 + ks * 32);
        #pragma unroll
        for (int ni = 0; ni < 4; ++ni)
            bfv[ni] = *(const bf16x8*)(Bbase + (size_t)ni * 16 * K2 + ks * 32);
        #pragma unroll
        for (int mi = 0; mi < 4; ++mi)
            #pragma unroll
            for (int ni = 0; ni < 4; ++ni)
                acc[mi][ni] = __builtin_amdgcn_mfma_f32_16x16x32_bf16(
                    af[mi], bfv[ni], acc[mi][ni], 0, 0, 0);
    }

    if constexpr (MODE == 0) {
        // ---- two-pass 32 KB swizzled LDS epilogue ----
        __shared__ unsigned short Cs[64 * 256];
        float bvn[4];
        #pragma unroll
        for (int ni = 0; ni < 4; ++ni)
            bvn[ni] = biasCat[n0 + wn + ni * 16 + l15];

        #pragma unroll
        for (int p = 0; p < 2; ++p) {
            if (p) __syncthreads();
            #pragma unroll
            for (int mi2 = 0; mi2 < 2; ++mi2) {
                const int mi = p * 2 + mi2;
                #pragma unroll
                for (int j = 0; j < 4; ++j) {
                    const int lr = (wm >> 1) + mi2 * 16 + lg * 4 + j;   // [0,64)
                    const int xr = (lr & 7) << 3;
                    #pragma unroll
                    for (int ni = 0; ni < 4; ++ni) {
                        const int col = wn + ni * 16 + l15;
                        Cs[lr * 256 + (col ^ xr)] = f2bf(acc[mi][ni][j] + bvn[ni]);
                    }
                }
            }
            __syncthreads();

            if (bx < 2) {
                unsigned short* dst = bx ? Kb : Qb;
                #pragma unroll
                for (int c8 = 0; c8 < 4; ++c8) {
                    const int chunk = c8 * 512 + t;       // 0..2047
                    const int lr = chunk >> 5;
                    const int ec = (chunk & 31) * 8;
                    const int gr = m0 + ((lr < 32) ? (p * 32 + lr)
                                                   : (64 + p * 32 + (lr - 32)));
                    const bf16x8 v = *(const bf16x8*)&Cs[lr * 256 + (ec ^ ((lr & 7) << 3))];
                    *(bf16x8*)&dst[(size_t)gr * 256 + ec] = v;
                }
            } else {
                // V transposed: element idx = d*8+g  <-  source col c = g*32+d
                #pragma unroll
                for (int c8 = 0; c8 < 4; ++c8) {
                    const int chunk = c8 * 512 + t;
                    const int lr = chunk >> 5;
                    const int ec = (chunk & 31) * 8;
                    const int gr = m0 + ((lr < 32) ? (p * 32 + lr)
                                                   : (64 + p * 32 + (lr - 32)));
                    const int d  = ec >> 3;
                    const int xr = (lr & 7) << 3;
                    bf16x8 v;
                    #pragma unroll
                    for (int g = 0; g < 8; ++g)
                        v[g] = (short)Cs[lr * 256 + ((g * 32 + d) ^ xr)];
                    *(bf16x8*)&Vb[(size_t)gr * 256 + ec] = v;
                }
            }
        }
    } else {
        // ---- fp32 out + cnt-weighted bias, direct stores ----
        #pragma unroll
        for (int mi = 0; mi < 4; ++mi)
            #pragma unroll
            for (int j = 0; j < 4; ++j) {
                const int row = m0 + wm + mi * 16 + lg * 4 + j;
                if (row < N_NODES) {
                    const float4 cv = cnt4[row];
                    #pragma unroll
                    for (int ni = 0; ni < 4; ++ni) {
                        const int col = wn + ni * 16 + l15;
                        Cout[(size_t)row * 128 + col] = acc[mi][ni][j]
                            + cv.x * eew[col] + cv.y * eew[128 + col]
                            + cv.z * eew[256 + col] + cv.w * bo[col];
                    }
                }
            }
    }
}

// ---------------------------------------------------------------------------
// Conversions / weight prep
// ---------------------------------------------------------------------------
__global__ __launch_bounds__(256)
void conv_nf_kernel(const float4* __restrict__ nf4, unsigned short* __restrict__ A2)
{
    const int tid = blockIdx.x * 256 + threadIdx.x;
    if (tid >= N_NODES * 32) return;
    const int m = tid >> 5, k4 = (tid & 31) * 4;
    const float4 v = nf4[tid];
    ushort4 hi;
    hi.x = f2bf(v.x); hi.y = f2bf(v.y); hi.z = f2bf(v.z); hi.w = f2bf(v.w);
    *reinterpret_cast<ushort4*>(&A2[(size_t)m * 128 + k4]) = hi;
}

__global__ __launch_bounds__(256)
void prep_kernel(const float* __restrict__ Wq, const float* __restrict__ Wk,
                 const float* __restrict__ Wv, const float* __restrict__ bq,
                 const float* __restrict__ bk, const float* __restrict__ bv,
                 const float* __restrict__ Wo, const float* __restrict__ ee,
                 unsigned short* __restrict__ B2qkv, unsigned short* __restrict__ B2o,
                 float* __restrict__ biasCat, float* __restrict__ eew)
{
    const int bid = blockIdx.x, t = threadIdx.x;
    if (bid < 384) {
        const int tid = bid * 256 + t;          // 768*128
        const int r = tid >> 7, k = tid & 127;
        const float* W = (r < 256) ? Wq : (r < 512) ? Wk : Wv;
        B2qkv[(size_t)r * 128 + k] = f2bf(W[(size_t)(r & 255) * 128 + k]);
        if (k == 0) {
            const float* b = (r < 256) ? bq : (r < 512) ? bk : bv;
            biasCat[r] = b[r & 255];
        }
    } else if (bid < 512) {
        const int tid = (bid - 384) * 256 + t;  // 128*256
        const int r = tid >> 8, k = tid & 255;
        B2o[(size_t)r * 256 + k] = f2bf(Wo[(size_t)r * 256 + k]);
    } else if (t < 128) {
        float a0 = 0.f, a1 = 0.f, a2 = 0.f;
        for (int k = 0; k < 256; ++k) {
            const float w = Wo[(size_t)t * 256 + k];
            a0 += ee[k] * w; a1 += ee[256 + k] * w; a2 += ee[512 + k] * w;
        }
        eew[t] = a0; eew[128 + t] = a1; eew[256 + t] = a2;
    }
}

// ---------------------------------------------------------------------------
// CSR build: hist -> hierarchical scan -> scatter
// ---------------------------------------------------------------------------
__global__ __launch_bounds__(256)
void hist_kernel(const int* __restrict__ edges, int* __restrict__ deg)
{
    const int e = blockIdx.x * 256 + threadIdx.x;
    if (e < N_EDGES) atomicAdd(&deg[edges[2 * e]], 1);
}

__global__ __launch_bounds__(256)
void scan_part1(const int* __restrict__ deg, int* __restrict__ blockSum)
{
    const int t = threadIdx.x;
    const int i = blockIdx.x * 256 + t;
    int v = (i < N_NODES) ? deg[i] : 0;
    #pragma unroll
    for (int o = 1; o < 64; o <<= 1) v += __shfl_xor(v, o);
    __shared__ int ws[4];
    if ((t & 63) == 0) ws[t >> 6] = v;
    __syncthreads();
    if (t == 0) blockSum[blockIdx.x] = ws[0] + ws[1] + ws[2] + ws[3];
}

__global__ __launch_bounds__(256)
void scan_part2(const int* __restrict__ blockSum, int* __restrict__ blockBase,
                int* __restrict__ rowStart)
{
    __shared__ int lds[256];
    const int t = threadIdx.x;
    lds[t] = (t < NBLK) ? blockSum[t] : 0;
    __syncthreads();
    #pragma unroll
    for (int o = 1; o < 256; o <<= 1) {
        const int u = (t >= o) ? lds[t - o] : 0;
        __syncthreads();
        lds[t] += u;
        __syncthreads();
    }
    if (t < NBLK) blockBase[t] = (t == 0) ? 0 : lds[t - 1];
    if (t == 0) rowStart[N_NODES] = N_EDGES;
}

__global__ __launch_bounds__(256)
void scan_part3(const int* __restrict__ deg, const int* __restrict__ blockBase,
                int* __restrict__ rowStart, int* __restrict__ cursor)
{
    const int t = threadIdx.x;
    const int lane = t & 63, wid = t >> 6;
    const int i = blockIdx.x * 256 + t;
    const int d = (i < N_NODES) ? deg[i] : 0;
    int x = d;
    #pragma unroll
    for (int o = 1; o < 64; o <<= 1) {
        const int u = __shfl_up(x, o);
        if (lane >= o) x += u;
    }
    __shared__ int wtot[4];
    if (lane == 63) wtot[wid] = x;
    __syncthreads();
    int wo = 0;
    #pragma unroll
    for (int wi = 0; wi < 3; ++wi) wo += (wi < wid) ? wtot[wi] : 0;
    const int excl = blockBase[blockIdx.x] + wo + x - d;
    if (i < N_NODES) { rowStart[i] = excl; cursor[i] = excl; }
}

__global__ __launch_bounds__(256)
void scatter_kernel(const int* __restrict__ edges, const int* __restrict__ etypes,
                    int* __restrict__ cursor, int* __restrict__ packed)
{
    const int e = blockIdx.x * 256 + threadIdx.x;
    if (e < N_EDGES) {
        const int pos = atomicAdd(&cursor[edges[2 * e]], 1);
        packed[pos] = edges[2 * e + 1] | (etypes[e] << 20);
    }
}

// ---------------------------------------------------------------------------
// MFMA gather attention (unchanged): one wave per src node,
// 2 edges per iteration as a block-diagonal 16x16 problem.
// ---------------------------------------------------------------------------
__global__ __launch_bounds__(256)
void node_gather_kernel(const int* __restrict__ packed, const int* __restrict__ rowStart,
                        const unsigned short* __restrict__ Qb,
                        const unsigned short* __restrict__ Kb,
                        const unsigned short* __restrict__ Vb,
                        unsigned short* __restrict__ accQ, float4* __restrict__ cnt4)
{
    const int lane = threadIdx.x & 63;
    const int n = blockIdx.x * 4 + (threadIdx.x >> 6);
    if (n >= N_NODES) return;
    const int l15 = lane & 15;
    const int lg  = lane >> 4;

    const bf16x8 qf = *(const bf16x8*)&Qb[(size_t)n * 256 + (l15 & 7) * 32 + lg * 8];

    f32x4 cpv0 = {0.f, 0.f, 0.f, 0.f};
    f32x4 cpv1 = {0.f, 0.f, 0.f, 0.f};
    int c0 = 0, c1 = 0, c2 = 0;

    const int lo = rowStart[n], hi = rowStart[n + 1];
    const bool validBase = ((l15 < 8) == (lg < 2));

    for (int idx = lo; idx < hi; idx += 2) {
        const int  p0  = packed[idx];
        const bool dup = (idx + 1 >= hi);
        const int  p1  = dup ? p0 : packed[idx + 1];
        const int  t0  = p0 & 0xFFFFF;
        const int  t1  = p1 & 0xFFFFF;
        const int  e0  = p0 >> 20;
        const int  e1  = p1 >> 20;
        c0 += (e0 == 0); c1 += (e0 == 1); c2 += (e0 == 2);
        if (!dup) { c0 += (e1 == 0); c1 += (e1 == 1); c2 += (e1 == 2); }

        const int tk = (l15 < 8) ? t0 : t1;
        const bf16x8 kf = *(const bf16x8*)&Kb[(size_t)tk * 256 + (l15 & 7) * 32 + lg * 8];

        const int tv = (lg < 2) ? t0 : t1;
        const unsigned short* vrow = &Vb[(size_t)tv * 256 + (lg & 1) * 4];
        const bf16x4 vf0 = *(const bf16x4*)&vrow[l15 * 8];
        const bf16x4 vf1 = *(const bf16x4*)&vrow[(l15 + 16) * 8];

        f32x4 s = __builtin_amdgcn_mfma_f32_16x16x32_bf16(kf, qf, (f32x4){0.f, 0.f, 0.f, 0.f}, 0, 0, 0);
        const float SC = 0.17677669529663687f;
        const float s0 = s[0] * SC, s1 = s[1] * SC, s2 = s[2] * SC, s3 = s[3] * SC;

        float mx = fmaxf(fmaxf(s0, s1), fmaxf(s2, s3));
        mx = fmaxf(mx, __shfl_xor(mx, 16));
        const float ex0 = __expf(s0 - mx), ex1 = __expf(s1 - mx);
        const float ex2 = __expf(s2 - mx), ex3 = __expf(s3 - mx);
        float sum = ex0 + ex1 + ex2 + ex3;
        sum += __shfl_xor(sum, 16);
        const float inv = 1.0f / sum;

        const bool valid = validBase && !(dup && (l15 >= 8));
        bf16x4 pa;
        pa[0] = valid ? (short)f2bf(ex0 * inv) : (short)0;
        pa[1] = valid ? (short)f2bf(ex1 * inv) : (short)0;
        pa[2] = valid ? (short)f2bf(ex2 * inv) : (short)0;
        pa[3] = valid ? (short)f2bf(ex3 * inv) : (short)0;

        cpv0 = __builtin_amdgcn_mfma_f32_16x16x16bf16_1k(pa, vf0, cpv0, 0, 0, 0);
        cpv1 = __builtin_amdgcn_mfma_f32_16x16x16bf16_1k(pa, vf1, cpv1, 0, 0, 0);
    }

    #pragma unroll
    for (int j = 0; j < 4; ++j) {
        cpv0[j] += __shfl_xor(cpv0[j], 32);
        cpv1[j] += __shfl_xor(cpv1[j], 32);
    }

    if (lane < 32) {
        unsigned short* row = &accQ[(size_t)n * 256];
        #pragma unroll
        for (int j = 0; j < 4; ++j) {
            const int h = lg * 4 + j;
            row[h * 32 + l15]      = f2bf(cpv0[j]);
            row[h * 32 + 16 + l15] = f2bf(cpv1[j]);
        }
    }
    if (lane == 0)
        cnt4[n] = make_float4((float)c0, (float)c1, (float)c2, (float)(hi - lo));
}

// ---------------------------------------------------------------------------
extern "C" void kernel_launch(void* const* d_in, const int* in_sizes, int n_in,
                              void* d_out, int out_size, void* d_ws, size_t ws_size,
                              hipStream_t stream)
{
    const float* nf      = (const float*)d_in[0];
    const int*   edges   = (const int*)d_in[1];
    const int*   etypes  = (const int*)d_in[2];
    const float* Wq      = (const float*)d_in[3];
    const float* bq      = (const float*)d_in[4];
    const float* Wk      = (const float*)d_in[5];
    const float* bk      = (const float*)d_in[6];
    const float* Wv      = (const float*)d_in[7];
    const float* bv      = (const float*)d_in[8];
    const float* ee      = (const float*)d_in[9];
    const float* Wo      = (const float*)d_in[10];
    const float* bo      = (const float*)d_in[11];
    float* out = (float*)d_out;

    char* ws = (char*)d_ws;
    size_t off = 0;
    auto alloc = [&](size_t bytes) -> void* {
        void* p = ws + off;
        off = (off + bytes + 255) & ~(size_t)255;
        return p;
    };
    unsigned short* A2    = (unsigned short*)alloc((size_t)M_PAD * 128 * 2);
    unsigned short* B2qkv = (unsigned short*)alloc((size_t)768 * 128 * 2);
    unsigned short* B2o   = (unsigned short*)alloc((size_t)128 * 256 * 2);
    float*          biasC = (float*)alloc(768 * sizeof(float));
    float*          eew   = (float*)alloc(384 * sizeof(float));
    unsigned short* Qb    = (unsigned short*)alloc((size_t)M_PAD * 256 * 2);
    unsigned short* Kb    = (unsigned short*)alloc((size_t)M_PAD * 256 * 2);
    unsigned short* Vb    = (unsigned short*)alloc((size_t)M_PAD * 256 * 2);
    unsigned short* accQ  = (unsigned short*)alloc((size_t)M_PAD2 * 256 * 2);
    float4* cnt4 = (float4*)alloc((size_t)N_NODES * sizeof(float4));
    int*    deg  = (int*)alloc((size_t)N_NODES * sizeof(int));
    int*    rowS = (int*)alloc((size_t)(N_NODES + 1) * sizeof(int));
    int*    curs = (int*)alloc((size_t)N_NODES * sizeof(int));
    int*    pck  = (int*)alloc((size_t)N_EDGES * sizeof(int));
    int*    bSum = (int*)alloc((size_t)NBLK * sizeof(int));
    int*    bBase= (int*)alloc((size_t)NBLK * sizeof(int));

    const dim3 blk(256);

    // conversions + weight prep
    conv_nf_kernel<<<dim3((N_NODES * 32 + 255) / 256), blk, 0, stream>>>((const float4*)nf, A2);
    prep_kernel<<<dim3(513), blk, 0, stream>>>(Wq, Wk, Wv, bq, bk, bv, Wo, ee, B2qkv, B2o, biasC, eew);

    // CSR build (hierarchical scan)
    hipMemsetAsync(deg, 0, (size_t)N_NODES * sizeof(int), stream);
    hist_kernel<<<dim3((N_EDGES + 255) / 256), blk, 0, stream>>>(edges, deg);
    scan_part1<<<dim3(NBLK), blk, 0, stream>>>(deg, bSum);
    scan_part2<<<dim3(1), blk, 0, stream>>>(bSum, bBase, rowS);
    scan_part3<<<dim3(NBLK), blk, 0, stream>>>(deg, bBase, rowS, curs);
    scatter_kernel<<<dim3((N_EDGES + 255) / 256), blk, 0, stream>>>(edges, etypes, curs, pck);

    // fused QKV projection (fragment-direct MFMA): [50048 x 128] @ [768 x 128]^T
    mfma_gemm<0><<<dim3(3, M_PAD / 128), dim3(512), 0, stream>>>(
        A2, B2qkv, biasC, Qb, Kb, Vb, nullptr, nullptr, nullptr, nullptr);

    // MFMA gather attention
    node_gather_kernel<<<dim3((N_NODES + 3) / 4), blk, 0, stream>>>(
        pck, rowS, Qb, Kb, Vb, accQ, cnt4);

    // output projection (fragment-direct MFMA): [50176 x 256] @ [128 x 256]^T
    mfma_gemm<1><<<dim3(1, M_PAD2 / 64), dim3(128), 0, stream>>>(
        accQ, B2o, nullptr, nullptr, nullptr, nullptr, eew, bo, cnt4, out);
}